// Round 10
// baseline (411.107 us; speedup 1.0000x reference)
//
#include <hip/hip_runtime.h>
#include <hip/hip_bf16.h>

typedef __attribute__((ext_vector_type(8))) short bf16x8;
typedef __attribute__((ext_vector_type(8))) unsigned short u16x8;
typedef __attribute__((ext_vector_type(4))) float f32x4;

__device__ __forceinline__ unsigned short f2bf(float f) {
  union { float f; unsigned int i; } v; v.f = f;
  unsigned int r = v.i + 0x7FFFu + ((v.i >> 16) & 1u);  // RNE
  return (unsigned short)(r >> 16);
}
// fast round-to-nearest (ties-away) pack of two f32 -> packed bf16x2
__device__ __forceinline__ unsigned int pack2bf_rn(float a, float b) {
  union { float f; unsigned int i; } x, y; x.f = a; y.f = b;
  return ((x.i + 0x8000u) >> 16) | ((y.i + 0x8000u) & 0xFFFF0000u);
}
// single-instruction pack: dst.lo = bf16(a) [RNE], dst.hi = bf16(b)
__device__ __forceinline__ unsigned int cvtpk(float a, float b) {
  unsigned int r;
  asm("v_cvt_pk_bf16_f32 %0, %1, %2" : "=v"(r) : "v"(a), "v"(b));
  return r;
}
// raw HW exp2: 1 TRANS instr, no ocml range-split (inputs here are either
// > -200 (live) or ~ -14400 (masked -> flush to 0, desired). ~1 ulp, far
// below the bf16 quantization applied immediately after.
__device__ __forceinline__ float fexp2(float x) {
  float r;
  asm("v_exp_f32 %0, %1" : "=v"(r) : "v"(x));
  return r;
}
// async global->LDS, 16B per lane; LDS dest = wave-uniform base + lane*16
__device__ __forceinline__ void gll16(const unsigned short* g, unsigned short* l) {
  __builtin_amdgcn_global_load_lds(
      (const __attribute__((address_space(1))) unsigned int*)g,
      (__attribute__((address_space(3))) unsigned int*)l, 16, 0, 0);
}

// ---------------- fused prep: hs cast + both weight transposes ----------------
__device__ __forceinline__ void transpose32(const float* in, unsigned short* out,
                                            long in_rs, long out_rs, int c0, int r0,
                                            unsigned short (*tile)[33]) {
  int tx = threadIdx.x & 31, ty = threadIdx.x >> 5;
#pragma unroll
  for (int i = 0; i < 32; i += 8)
    tile[ty + i][tx] = f2bf(in[(long)(r0 + ty + i) * in_rs + c0 + tx]);
  __syncthreads();
#pragma unroll
  for (int i = 0; i < 32; i += 8)
    out[(long)(c0 + ty + i) * out_rs + r0 + tx] = tile[tx][ty + i];
}

__global__ void prep_k(const float* __restrict__ hs, unsigned short* __restrict__ hsb,
                       const float* __restrict__ Wa, unsigned short* __restrict__ WtA,
                       const float* __restrict__ Wp, unsigned short* __restrict__ WtP) {
  __shared__ unsigned short tile[32][33];
  const int bid = blockIdx.x;
  if (bid < 4096) {
    long i = ((long)bid * 256 + threadIdx.x) * 8;
    float4 a = *(const float4*)(hs + i);
    float4 b = *(const float4*)(hs + i + 4);
    u16x8 o;
    o[0] = f2bf(a.x); o[1] = f2bf(a.y); o[2] = f2bf(a.z); o[3] = f2bf(a.w);
    o[4] = f2bf(b.x); o[5] = f2bf(b.y); o[6] = f2bf(b.z); o[7] = f2bf(b.w);
    *(u16x8*)(hsb + i) = o;
  } else if (bid < 16384) {
    int r = bid - 4096;                    // 192 x 64
    int bx = r % 192, by = r / 192;
    transpose32(Wa, WtA, 6144, 2048, bx * 32, by * 32, tile);
  } else {
    int r = bid - 16384;                   // 64 x 64
    int bx = r & 63, by = r >> 6;
    transpose32(Wp, WtP, 2048, 2048, bx * 32, by * 32, tile);
  }
}

// ================== BK=64 GEMM staging/fragment helpers ==================
// LDS tile [128][64] bf16, XOR-swizzled (physical col-block p of row r holds
// logical p ^ (r&7)); double-buffered. Staged via gll16 linear dest with the
// per-lane global SOURCE col pre-permuted (both-sides-or-neither rule).
// Prefetch-dbuf (attn-proven): stage kb+64 into buf^1 while computing buf ->
// zero exposed staging latency, 1 barrier/iter instead of 2.

// ---- qkv GEMM with fused scatter epilogue (BK=64, dbuf) ----
__global__ __launch_bounds__(256) void gemm_qkv(
    const unsigned short* __restrict__ A,   // [4096][2048] bf16
    const unsigned short* __restrict__ Bt,  // [6144][2048] bf16
    const float* __restrict__ bias,         // [6144]
    unsigned short* __restrict__ qQ,        // [4096][2048]
    unsigned short* __restrict__ k1p, unsigned short* __restrict__ k2p,
    unsigned short* __restrict__ vp) {
  const int K = 2048;
  __shared__ unsigned short As[2 * 128 * 64];
  __shared__ unsigned short Bs[2 * 128 * 64];
  const int m0 = blockIdx.y * 128, n0 = blockIdx.x * 128;
  const int tid = threadIdx.x, lane = tid & 63, wave = tid >> 6;
  const int wm = (wave >> 1) * 64, wn = (wave & 1) * 64;
  const int quad = lane >> 4, l15 = lane & 15;
  const int sw = l15 & 7;
  const int arow = wave * 8 + (lane >> 3);
  const int acol = ((lane & 7) ^ ((lane >> 3) & 7)) * 8;

  f32x4 acc[4][4] = {};
  const unsigned short* Ap = A + (long)(m0 + arow) * K + acol;
  const unsigned short* Bp = Bt + (long)(n0 + arow) * K + acol;
  unsigned short* AsW = As + wave * 512;
  unsigned short* BsW = Bs + wave * 512;

  // prologue: stage kb=0 into buffer 0
#pragma unroll
  for (int s = 0; s < 4; s++) {
    gll16(Ap + (long)s * 32 * K, AsW + s * 2048);
    gll16(Bp + (long)s * 32 * K, BsW + s * 2048);
  }

  for (int kb = 0; kb < K; kb += 64) {
    const int cur = (kb >> 6) & 1;
    __syncthreads();  // buf[cur] staged; prev iter's ds_reads done -> buf[cur^1] free
    if (kb + 64 < K) {
      unsigned short* dA = AsW + (cur ^ 1) * 8192;
      unsigned short* dB = BsW + (cur ^ 1) * 8192;
#pragma unroll
      for (int s = 0; s < 4; s++) {
        gll16(Ap + (long)s * 32 * K + kb + 64, dA + s * 2048);
        gll16(Bp + (long)s * 32 * K + kb + 64, dB + s * 2048);
      }
    }
    const unsigned short* Ab = As + cur * 8192;
    const unsigned short* Bb = Bs + cur * 8192;
#pragma unroll
    for (int ks = 0; ks < 2; ks++) {
      bf16x8 af[4], bfr[4];
#pragma unroll
      for (int t = 0; t < 4; t++)
        af[t] = *(const bf16x8*)&Ab[(wm + t * 16 + l15) * 64 + (((ks * 4 + quad) ^ sw) << 3)];
#pragma unroll
      for (int t = 0; t < 4; t++)
        bfr[t] = *(const bf16x8*)&Bb[(wn + t * 16 + l15) * 64 + (((ks * 4 + quad) ^ sw) << 3)];
#pragma unroll
      for (int i = 0; i < 4; i++)
#pragma unroll
        for (int j = 0; j < 4; j++)
          acc[i][j] = __builtin_amdgcn_mfma_f32_16x16x32_bf16(af[i], bfr[j], acc[i][j], 0, 0, 0);
    }
  }

  const int ncol = n0 + wn;  // wave-uniform 64-col base
  if (ncol < 2048) {
    // ---- Q region: row-major [4096][2048] ----
#pragma unroll
    for (int j = 0; j < 4; j++) {
      int n = ncol + j * 16 + l15;
      float bv = bias[n];
#pragma unroll
      for (int i = 0; i < 4; i++) {
        int mr = m0 + wm + i * 16 + quad * 4;
#pragma unroll
        for (int r = 0; r < 4; r++)
          qQ[(long)(mr + r) * 2048 + n] = f2bf(acc[i][j][r] + bv);
      }
    }
  } else if (ncol < 4096) {
    // ---- K region: kpack layout tile[(b,h,t)][row*64 + (c^(row&7))*8 + e] ----
    unsigned short* kp = (ncol >= 3072) ? k2p : k1p;
#pragma unroll
    for (int j = 0; j < 4; j++) {
      int n = ncol + j * 16 + l15;
      float bv = bias[n];
      int kk = (n - 2048) & 1023;
      int h = kk >> 6, c = (kk >> 3) & 7, e = kk & 7;
#pragma unroll
      for (int i = 0; i < 4; i++) {
        int mr = m0 + wm + i * 16 + quad * 4;
        int b = mr >> 11, s = mr & 2047;
        long tb2 = ((long)(b * 16 + h) * 32 + (s >> 6)) * 4096 + e;
        int row0 = s & 63;
#pragma unroll
        for (int r = 0; r < 4; r++) {
          int row = row0 + r;
          kp[tb2 + row * 64 + ((c ^ (row & 7)) << 3)] = f2bf(acc[i][j][r] + bv);
        }
      }
    }
  } else {
    // ---- V region: vpack layout tile[(b,h,t)][d*64 + (cc^(d&7))*8 + (s&7)] ----
#pragma unroll
    for (int j = 0; j < 4; j++) {
      int n = ncol + j * 16 + l15;
      float bv = bias[n];
      int vv = n - 4096;
      int h = vv >> 7, d = vv & 127;
#pragma unroll
      for (int i = 0; i < 4; i++) {
        int mr = m0 + wm + i * 16 + quad * 4;
        int b = mr >> 11, s = mr & 2047;
        int cc = (s & 63) >> 3;
        long dst = ((long)(b * 16 + h) * 32 + (s >> 6)) * 8192 + d * 64 +
                   ((cc ^ (d & 7)) << 3) + (quad & 1) * 4;
        uint2 st;
        st.x = pack2bf_rn(acc[i][j][0] + bv, acc[i][j][1] + bv);
        st.y = pack2bf_rn(acc[i][j][2] + bv, acc[i][j][3] + bv);
        *(uint2*)&vp[dst] = st;
      }
    }
  }
}

// ---------- GEMM (BK=64, dbuf): C = A . Bt^T + bias, f32 out ----------
__global__ __launch_bounds__(256) void gemm_bt_f32(
    const unsigned short* __restrict__ A,   // [M][K]
    const unsigned short* __restrict__ Bt,  // [N][K]
    const float* __restrict__ bias,         // [N]
    float* __restrict__ C, int K, int ldc) {
  __shared__ unsigned short As[2 * 128 * 64];
  __shared__ unsigned short Bs[2 * 128 * 64];
  const int m0 = blockIdx.y * 128, n0 = blockIdx.x * 128;
  const int tid = threadIdx.x, lane = tid & 63, wave = tid >> 6;
  const int wm = (wave >> 1) * 64, wn = (wave & 1) * 64;
  const int quad = lane >> 4, l15 = lane & 15;
  const int sw = l15 & 7;
  const int arow = wave * 8 + (lane >> 3);
  const int acol = ((lane & 7) ^ ((lane >> 3) & 7)) * 8;

  f32x4 acc[4][4] = {};
  const unsigned short* Ap = A + (long)(m0 + arow) * K + acol;
  const unsigned short* Bp = Bt + (long)(n0 + arow) * K + acol;
  unsigned short* AsW = As + wave * 512;
  unsigned short* BsW = Bs + wave * 512;

  // prologue: stage kb=0 into buffer 0
#pragma unroll
  for (int s = 0; s < 4; s++) {
    gll16(Ap + (long)s * 32 * K, AsW + s * 2048);
    gll16(Bp + (long)s * 32 * K, BsW + s * 2048);
  }

  for (int kb = 0; kb < K; kb += 64) {
    const int cur = (kb >> 6) & 1;
    __syncthreads();
    if (kb + 64 < K) {
      unsigned short* dA = AsW + (cur ^ 1) * 8192;
      unsigned short* dB = BsW + (cur ^ 1) * 8192;
#pragma unroll
      for (int s = 0; s < 4; s++) {
        gll16(Ap + (long)s * 32 * K + kb + 64, dA + s * 2048);
        gll16(Bp + (long)s * 32 * K + kb + 64, dB + s * 2048);
      }
    }
    const unsigned short* Ab = As + cur * 8192;
    const unsigned short* Bb = Bs + cur * 8192;
#pragma unroll
    for (int ks = 0; ks < 2; ks++) {
      bf16x8 af[4], bfr[4];
#pragma unroll
      for (int t = 0; t < 4; t++)
        af[t] = *(const bf16x8*)&Ab[(wm + t * 16 + l15) * 64 + (((ks * 4 + quad) ^ sw) << 3)];
#pragma unroll
      for (int t = 0; t < 4; t++)
        bfr[t] = *(const bf16x8*)&Bb[(wn + t * 16 + l15) * 64 + (((ks * 4 + quad) ^ sw) << 3)];
#pragma unroll
      for (int i = 0; i < 4; i++)
#pragma unroll
        for (int j = 0; j < 4; j++)
          acc[i][j] = __builtin_amdgcn_mfma_f32_16x16x32_bf16(af[i], bfr[j], acc[i][j], 0, 0, 0);
    }
  }
#pragma unroll
  for (int j = 0; j < 4; j++) {
    int n = n0 + wn + j * 16 + l15;
    float bv = bias[n];
#pragma unroll
    for (int i = 0; i < 4; i++) {
      int mr = m0 + wm + i * 16 + quad * 4;
#pragma unroll
      for (int r = 0; r < 4; r++)
        C[(long)(mr + r) * ldc + n] = acc[i][j][r] + bv;
    }
  }
}

// ------- differential flash attention (S^T form, fixed-max, q32/wave, dbuf) -------
// 1-D grid 512, block 256 (4 waves). Wave w owns q rows [w*32, w*32+32).
// XCD swizzle: wgid = (bid&7)*64 + (bid>>3) -> XCD j owns 4 (b,h) K/V streams
// x 16 q-tiles -> 16-way L2 reuse (proven FETCH 139->25MB).
__global__ __launch_bounds__(256, 2) void attn_k(
    const unsigned short* __restrict__ qQ,   // [B*S][2048] bf16 (q only)
    const unsigned short* __restrict__ k1p,  // packed swizzled tiles
    const unsigned short* __restrict__ k2p,
    const unsigned short* __restrict__ vp,
    const float* __restrict__ mask,          // [B][S] f32
    const float* __restrict__ lamp,          // [1] f32
    unsigned short* __restrict__ out) {      // [B*S][2048] bf16
  __shared__ unsigned short k1s[2 * 4096];
  __shared__ unsigned short k2s[2 * 4096];
  __shared__ unsigned short vts[2 * 8192];
  __shared__ unsigned short pls[4 * 2048];  // [wave][qt*2+st][q16 x k32 swizzled]
  const int bid = blockIdx.x;
  const int wgid = (bid & 7) * 64 + (bid >> 3);
  const int bh = wgid >> 4;                 // 0..31 = b*16+h
  const int q0 = (wgid & 15) * 128;
  const int b = bh >> 4, h = bh & 15;
  const int tid = threadIdx.x, lane = tid & 63, wave = tid >> 6;
  const int quad = lane >> 4, l15 = lane & 15;
  const long rowq = (long)b * 2048 + q0;
  const int sw = l15 & 7;

  // Q fragments (B-operand layout), 2 q-tiles per wave, straight from global
  bf16x8 aq1[2][2], aq2[2][2];
#pragma unroll
  for (int qt = 0; qt < 2; qt++) {
    const unsigned short* qr =
        qQ + (rowq + wave * 32 + qt * 16 + l15) * 2048 + h * 64 + quad * 8;
    aq1[qt][0] = *(const bf16x8*)qr;
    aq1[qt][1] = *(const bf16x8*)(qr + 32);
    aq2[qt][0] = *(const bf16x8*)(qr + 1024);
    aq2[qt][1] = *(const bf16x8*)(qr + 1056);
  }
  f32x4 o1[2][8] = {}, o2[2][8] = {};
  // l-sums accumulated via ones-MFMA: C[col=l15] = sum_k P^T[k][col], dup'd over rows
  f32x4 l1a[2] = {}, l2a[2] = {};
  bf16x8 ones;
#pragma unroll
  for (int e = 0; e < 8; e++) ones[e] = (short)0x3F80;  // bf16 1.0
  // log2e-scaled domain, fixed max 0: p = exp2(s*SL + (1-m)*(-1e4*log2e))
  const float SL = 0.08838834764831845f * 1.4426950408889634f;
  const float ML = 1.4426950408889634e4f;
  const long tb = (long)bh * 32;
  unsigned short* pw = pls + wave * 2048;

  // initial stage of tile 0 into buffer 0
  {
    const unsigned short* k1t = k1p + tb * 4096 + tid * 8;
    const unsigned short* k2t = k2p + tb * 4096 + tid * 8;
    const unsigned short* vtt = vp + tb * 8192 + tid * 8;
    gll16(k1t, k1s + wave * 512);
    gll16(k1t + 2048, k1s + 2048 + wave * 512);
    gll16(k2t, k2s + wave * 512);
    gll16(k2t + 2048, k2s + 2048 + wave * 512);
#pragma unroll
    for (int rr = 0; rr < 4; rr++)
      gll16(vtt + rr * 2048, vts + rr * 2048 + wave * 512);
  }

  for (int t = 0; t < 32; t++) {
    const int cb = t & 1;
    __syncthreads();  // drains vmcnt: tile t staged; buffer cb^1 free
    // mask loads FIRST: oldest in vmcnt queue, so waiting for them does not
    // force the 12 prefetch global_load_lds to retire mid-iteration
    float4 mq[4];
#pragma unroll
    for (int nt = 0; nt < 4; nt++)
      mq[nt] = *(const float4*)(mask + (long)b * 2048 + t * 64 + nt * 16 + quad * 4);
    if (t < 31) {     // prefetch tile t+1 into other buffer
      const unsigned short* k1t = k1p + (tb + t + 1) * 4096 + tid * 8;
      const unsigned short* k2t = k2p + (tb + t + 1) * 4096 + tid * 8;
      const unsigned short* vtt = vp + (tb + t + 1) * 8192 + tid * 8;
      unsigned short* d1 = k1s + (cb ^ 1) * 4096 + wave * 512;
      unsigned short* d2 = k2s + (cb ^ 1) * 4096 + wave * 512;
      unsigned short* dv = vts + (cb ^ 1) * 8192 + wave * 512;
      gll16(k1t, d1);
      gll16(k1t + 2048, d1 + 2048);
      gll16(k2t, d2);
      gll16(k2t + 2048, d2 + 2048);
#pragma unroll
      for (int rr = 0; rr < 4; rr++)
        gll16(vtt + rr * 2048, dv + rr * 2048);
    }

#pragma unroll
    for (int half = 0; half < 2; half++) {
      // S^T = K . Q^T for k-half (32 k rows): C row=k (quad*4+r), col=q (l15)
      f32x4 s1[2][2] = {}, s2[2][2] = {};
#pragma unroll
      for (int np = 0; np < 2; np++) {
        const int row = cb * 4096 + (half * 32 + np * 16 + l15) * 64;
#pragma unroll
        for (int ks = 0; ks < 2; ks++) {
          const int p = ((ks * 4 + quad) ^ sw) * 8;
          bf16x8 kf1 = *(const bf16x8*)&k1s[row + p];
          bf16x8 kf2 = *(const bf16x8*)&k2s[row + p];
#pragma unroll
          for (int qt = 0; qt < 2; qt++) {
            s1[qt][np] = __builtin_amdgcn_mfma_f32_16x16x32_bf16(kf1, aq1[qt][ks], s1[qt][np], 0, 0, 0);
            s2[qt][np] = __builtin_amdgcn_mfma_f32_16x16x32_bf16(kf2, aq2[qt][ks], s2[qt][np], 0, 0, 0);
          }
        }
      }
      // fixed-max softmax: p = exp2(s*SL + ma) via raw v_exp_f32
      float ma[2][4];
#pragma unroll
      for (int np = 0; np < 2; np++)
#pragma unroll
        for (int r = 0; r < 4; r++)
          ma[np][r] = fmaf(((const float*)&mq[half * 2 + np])[r], ML, -ML);
#pragma unroll
      for (int qt = 0; qt < 2; qt++)
#pragma unroll
        for (int np = 0; np < 2; np++) {
          // write slot s4 = k'>>2 = np*4+quad, physical pos (s4 ^ (l15&7))*4:
          // bank-pair = 8*(l15&1) + (s4^x) is injective -> optimal 4-way for b64
          const int addr = l15 * 32 + (((np * 4 + quad) ^ sw) << 2);
          uint2 w1, w2;
          w1.x = cvtpk(fexp2(fmaf(s1[qt][np][0], SL, ma[np][0])),
                       fexp2(fmaf(s1[qt][np][1], SL, ma[np][1])));
          w1.y = cvtpk(fexp2(fmaf(s1[qt][np][2], SL, ma[np][2])),
                       fexp2(fmaf(s1[qt][np][3], SL, ma[np][3])));
          w2.x = cvtpk(fexp2(fmaf(s2[qt][np][0], SL, ma[np][0])),
                       fexp2(fmaf(s2[qt][np][1], SL, ma[np][1])));
          w2.y = cvtpk(fexp2(fmaf(s2[qt][np][2], SL, ma[np][2])),
                       fexp2(fmaf(s2[qt][np][3], SL, ma[np][3])));
          *(uint2*)&pw[(qt * 2 + 0) * 512 + addr] = w1;
          *(uint2*)&pw[(qt * 2 + 1) * 512 + addr] = w2;
        }
      // (no explicit lgkm drain: per-wave DS in-order + compiler counted waits)
      // PV for this k-half: O^T += V^T . P^T  (V frag shared by 2qt x 2streams)
      bf16x8 f1[2], f2[2];
      {
        const int ra = l15 * 32 + (((quad * 2 + 0) ^ sw) << 2);
        const int rb = l15 * 32 + (((quad * 2 + 1) ^ sw) << 2);
#pragma unroll
        for (int qt = 0; qt < 2; qt++) {
          union { bf16x8 v; uint2 u2[2]; } g1, g2;
          g1.u2[0] = *(const uint2*)&pw[(qt * 2 + 0) * 512 + ra];
          g1.u2[1] = *(const uint2*)&pw[(qt * 2 + 0) * 512 + rb];
          g2.u2[0] = *(const uint2*)&pw[(qt * 2 + 1) * 512 + ra];
          g2.u2[1] = *(const uint2*)&pw[(qt * 2 + 1) * 512 + rb];
          f1[qt] = g1.v; f2[qt] = g2.v;
        }
      }
      // l-sums: ones(16x32) . P^T -> every lane gets full 32-k column sum for q=l15
#pragma unroll
      for (int qt = 0; qt < 2; qt++) {
        l1a[qt] = __builtin_amdgcn_mfma_f32_16x16x32_bf16(ones, f1[qt], l1a[qt], 0, 0, 0);
        l2a[qt] = __builtin_amdgcn_mfma_f32_16x16x32_bf16(ones, f2[qt], l2a[qt], 0, 0, 0);
      }
#pragma unroll
      for (int dn = 0; dn < 8; dn++) {
        const int pp = ((half * 4 + quad) ^ sw) * 8;
        bf16x8 vf = *(const bf16x8*)&vts[cb * 8192 + (dn * 16 + l15) * 64 + pp];
#pragma unroll
        for (int qt = 0; qt < 2; qt++) {
          o1[qt][dn] = __builtin_amdgcn_mfma_f32_16x16x32_bf16(vf, f1[qt], o1[qt][dn], 0, 0, 0);
          o2[qt][dn] = __builtin_amdgcn_mfma_f32_16x16x32_bf16(vf, f2[qt], o2[qt][dn], 0, 0, 0);
        }
      }
      // (no post-PV drain: pw rewrite next half is same-wave, DS in-order)
    }
  }
  // epilogue: out = O1/l1 - lam*O2/l2 (l already full sums, no reduce needed)
  float lam = lamp[0];
#pragma unroll
  for (int qt = 0; qt < 2; qt++) {
    float i1 = 1.f / l1a[qt][0], i2 = lam / l2a[qt][0];
    unsigned short* orow =
        out + (rowq + wave * 32 + qt * 16 + l15) * 2048 + h * 128 + quad * 4;
#pragma unroll
    for (int dn = 0; dn < 8; dn++) {
      uint2 st;
      st.x = cvtpk(o1[qt][dn][0] * i1 - o2[qt][dn][0] * i2,
                   o1[qt][dn][1] * i1 - o2[qt][dn][1] * i2);
      st.y = cvtpk(o1[qt][dn][2] * i1 - o2[qt][dn][2] * i2,
                   o1[qt][dn][3] * i1 - o2[qt][dn][3] * i2);
      *(uint2*)(orow + dn * 16) = st;
    }
  }
}

extern "C" void kernel_launch(void* const* d_in, const int* in_sizes, int n_in,
                              void* d_out, int out_size, void* d_ws, size_t ws_size,
                              hipStream_t stream) {
  (void)in_sizes; (void)n_in; (void)out_size; (void)ws_size;
  const float* hs   = (const float*)d_in[0];
  const float* mask = (const float*)d_in[1];
  const float* Wa   = (const float*)d_in[2];
  const float* ba   = (const float*)d_in[3];
  const float* Wp   = (const float*)d_in[4];
  const float* bp   = (const float*)d_in[5];
  const float* lam  = (const float*)d_in[6];
  float* out = (float*)d_out;
  unsigned short* ws = (unsigned short*)d_ws;

  // workspace (bf16 elems): 48Mi elems = 96 MiB
  unsigned short* hsb = ws;                                  // [4096][2048] (aliased by att)
  unsigned short* WtA = hsb + (long)4096 * 2048;             // [6144][2048]
  unsigned short* WtP = WtA + (long)6144 * 2048;             // [2048][2048]
  unsigned short* qQ  = WtP + (long)2048 * 2048;             // [4096][2048]
  unsigned short* K1p = qQ + (long)4096 * 2048;              // 2*16*32 tiles * 4096
  unsigned short* K2p = K1p + (long)2 * 16 * 2048 * 64;
  unsigned short* Vp  = K2p + (long)2 * 16 * 2048 * 64;      // 2*16*32 tiles * 8192
  unsigned short* att = hsb;                                 // alias (hsb dead after step 2)

  // 1) fused cast + weight transposes (1 launch)
  prep_k<<<20480, 256, 0, stream>>>(hs, hsb, Wa, WtA, Wp, WtP);
  // 2) qkv GEMM (BK=64, dbuf), 2-D grid
  gemm_qkv<<<dim3(48, 32), 256, 0, stream>>>(hsb, WtA, ba, qQ, K1p, K2p, Vp);
  // 3) differential flash attention (XCD-swizzled 1-D grid, 4 waves x 32q)
  attn_k<<<512, 256, 0, stream>>>(qQ, K1p, K2p, Vp, mask, lam, att);
  // 4) out = att @ W_proj + b_proj (BK=64, dbuf, 2-D grid)
  gemm_bt_f32<<<dim3(16, 32), 256, 0, stream>>>(att, WtP, bp, out, 2048, 2048);
}

// Round 11
// 394.071 us; speedup vs baseline: 1.0432x; 1.0432x over previous
//
#include <hip/hip_runtime.h>
#include <hip/hip_bf16.h>

typedef __attribute__((ext_vector_type(8))) short bf16x8;
typedef __attribute__((ext_vector_type(8))) unsigned short u16x8;
typedef __attribute__((ext_vector_type(4))) float f32x4;

__device__ __forceinline__ unsigned short f2bf(float f) {
  union { float f; unsigned int i; } v; v.f = f;
  unsigned int r = v.i + 0x7FFFu + ((v.i >> 16) & 1u);  // RNE
  return (unsigned short)(r >> 16);
}
// fast round-to-nearest (ties-away) pack of two f32 -> packed bf16x2
__device__ __forceinline__ unsigned int pack2bf_rn(float a, float b) {
  union { float f; unsigned int i; } x, y; x.f = a; y.f = b;
  return ((x.i + 0x8000u) >> 16) | ((y.i + 0x8000u) & 0xFFFF0000u);
}
// single-instruction pack: dst.lo = bf16(a) [RNE], dst.hi = bf16(b)
__device__ __forceinline__ unsigned int cvtpk(float a, float b) {
  unsigned int r;
  asm("v_cvt_pk_bf16_f32 %0, %1, %2" : "=v"(r) : "v"(a), "v"(b));
  return r;
}
// raw HW exp2: 1 TRANS instr, no ocml range-split (inputs here are either
// > -200 (live) or ~ -14400 (masked -> flush to 0, desired). ~1 ulp, far
// below the bf16 quantization applied immediately after.
__device__ __forceinline__ float fexp2(float x) {
  float r;
  asm("v_exp_f32 %0, %1" : "=v"(r) : "v"(x));
  return r;
}
// async global->LDS, 16B per lane; LDS dest = wave-uniform base + lane*16
__device__ __forceinline__ void gll16(const unsigned short* g, unsigned short* l) {
  __builtin_amdgcn_global_load_lds(
      (const __attribute__((address_space(1))) unsigned int*)g,
      (__attribute__((address_space(3))) unsigned int*)l, 16, 0, 0);
}

// ---------------- fused prep: hs cast + both weight transposes ----------------
__device__ __forceinline__ void transpose32(const float* in, unsigned short* out,
                                            long in_rs, long out_rs, int c0, int r0,
                                            unsigned short (*tile)[33]) {
  int tx = threadIdx.x & 31, ty = threadIdx.x >> 5;
#pragma unroll
  for (int i = 0; i < 32; i += 8)
    tile[ty + i][tx] = f2bf(in[(long)(r0 + ty + i) * in_rs + c0 + tx]);
  __syncthreads();
#pragma unroll
  for (int i = 0; i < 32; i += 8)
    out[(long)(c0 + ty + i) * out_rs + r0 + tx] = tile[tx][ty + i];
}

__global__ void prep_k(const float* __restrict__ hs, unsigned short* __restrict__ hsb,
                       const float* __restrict__ Wa, unsigned short* __restrict__ WtA,
                       const float* __restrict__ Wp, unsigned short* __restrict__ WtP) {
  __shared__ unsigned short tile[32][33];
  const int bid = blockIdx.x;
  if (bid < 4096) {
    long i = ((long)bid * 256 + threadIdx.x) * 8;
    float4 a = *(const float4*)(hs + i);
    float4 b = *(const float4*)(hs + i + 4);
    u16x8 o;
    o[0] = f2bf(a.x); o[1] = f2bf(a.y); o[2] = f2bf(a.z); o[3] = f2bf(a.w);
    o[4] = f2bf(b.x); o[5] = f2bf(b.y); o[6] = f2bf(b.z); o[7] = f2bf(b.w);
    *(u16x8*)(hsb + i) = o;
  } else if (bid < 16384) {
    int r = bid - 4096;                    // 192 x 64
    int bx = r % 192, by = r / 192;
    transpose32(Wa, WtA, 6144, 2048, bx * 32, by * 32, tile);
  } else {
    int r = bid - 16384;                   // 64 x 64
    int bx = r & 63, by = r >> 6;
    transpose32(Wp, WtP, 2048, 2048, bx * 32, by * 32, tile);
  }
}

// ================== BK=64 GEMM staging/fragment helpers ==================
// LDS tile [128][64] bf16 (16KB), XOR-swizzled: physical col-block p of row r
// holds logical col-block p ^ (r&7). Staged via gll16 linear dest with the
// per-lane global SOURCE col pre-permuted (rule: both-sides-or-neither).
// Synchronous 2-barrier staging: explicit dbuf REGRESSED (R10, 401->411) —
// runtime-cur LDS aliasing makes the compiler serialize prefetch into compute;
// 2-blocks/CU implicit overlap already hides staging (m99 regime).

// ---- qkv GEMM with fused scatter epilogue (BK=64) ----
__global__ __launch_bounds__(256) void gemm_qkv(
    const unsigned short* __restrict__ A,   // [4096][2048] bf16
    const unsigned short* __restrict__ Bt,  // [6144][2048] bf16
    const float* __restrict__ bias,         // [6144]
    unsigned short* __restrict__ qQ,        // [4096][2048]
    unsigned short* __restrict__ k1p, unsigned short* __restrict__ k2p,
    unsigned short* __restrict__ vp) {
  const int K = 2048;
  __shared__ unsigned short As[128 * 64];
  __shared__ unsigned short Bs[128 * 64];
  const int m0 = blockIdx.y * 128, n0 = blockIdx.x * 128;
  const int tid = threadIdx.x, lane = tid & 63, wave = tid >> 6;
  const int wm = (wave >> 1) * 64, wn = (wave & 1) * 64;
  const int quad = lane >> 4, l15 = lane & 15;
  const int sw = l15 & 7;
  // staging coords: row-in-site + swizzled source col-block
  const int arow = wave * 8 + (lane >> 3);
  const int acol = ((lane & 7) ^ ((lane >> 3) & 7)) * 8;

  f32x4 acc[4][4] = {};
  const unsigned short* Ap = A + (long)(m0 + arow) * K + acol;
  const unsigned short* Bp = Bt + (long)(n0 + arow) * K + acol;
  unsigned short* AsW = As + wave * 512;
  unsigned short* BsW = Bs + wave * 512;

  for (int kb = 0; kb < K; kb += 64) {
    __syncthreads();
#pragma unroll
    for (int s = 0; s < 4; s++) {
      gll16(Ap + (long)s * 32 * K + kb, AsW + s * 2048);
      gll16(Bp + (long)s * 32 * K + kb, BsW + s * 2048);
    }
    __syncthreads();
#pragma unroll
    for (int ks = 0; ks < 2; ks++) {
      bf16x8 af[4], bfr[4];
#pragma unroll
      for (int t = 0; t < 4; t++)
        af[t] = *(const bf16x8*)&As[(wm + t * 16 + l15) * 64 + (((ks * 4 + quad) ^ sw) << 3)];
#pragma unroll
      for (int t = 0; t < 4; t++)
        bfr[t] = *(const bf16x8*)&Bs[(wn + t * 16 + l15) * 64 + (((ks * 4 + quad) ^ sw) << 3)];
#pragma unroll
      for (int i = 0; i < 4; i++)
#pragma unroll
        for (int j = 0; j < 4; j++)
          acc[i][j] = __builtin_amdgcn_mfma_f32_16x16x32_bf16(af[i], bfr[j], acc[i][j], 0, 0, 0);
    }
  }

  const int ncol = n0 + wn;  // wave-uniform 64-col base
  if (ncol < 2048) {
    // ---- Q region: row-major [4096][2048] ----
#pragma unroll
    for (int j = 0; j < 4; j++) {
      int n = ncol + j * 16 + l15;
      float bv = bias[n];
#pragma unroll
      for (int i = 0; i < 4; i++) {
        int mr = m0 + wm + i * 16 + quad * 4;
#pragma unroll
        for (int r = 0; r < 4; r++)
          qQ[(long)(mr + r) * 2048 + n] = f2bf(acc[i][j][r] + bv);
      }
    }
  } else if (ncol < 4096) {
    // ---- K region: kpack layout tile[(b,h,t)][row*64 + (c^(row&7))*8 + e] ----
    unsigned short* kp = (ncol >= 3072) ? k2p : k1p;
#pragma unroll
    for (int j = 0; j < 4; j++) {
      int n = ncol + j * 16 + l15;
      float bv = bias[n];
      int kk = (n - 2048) & 1023;
      int h = kk >> 6, c = (kk >> 3) & 7, e = kk & 7;
#pragma unroll
      for (int i = 0; i < 4; i++) {
        int mr = m0 + wm + i * 16 + quad * 4;
        int b = mr >> 11, s = mr & 2047;
        long tb2 = ((long)(b * 16 + h) * 32 + (s >> 6)) * 4096 + e;
        int row0 = s & 63;
#pragma unroll
        for (int r = 0; r < 4; r++) {
          int row = row0 + r;
          kp[tb2 + row * 64 + ((c ^ (row & 7)) << 3)] = f2bf(acc[i][j][r] + bv);
        }
      }
    }
  } else {
    // ---- V region: vpack layout tile[(b,h,t)][d*64 + (cc^(d&7))*8 + (s&7)] ----
#pragma unroll
    for (int j = 0; j < 4; j++) {
      int n = ncol + j * 16 + l15;
      float bv = bias[n];
      int vv = n - 4096;
      int h = vv >> 7, d = vv & 127;
#pragma unroll
      for (int i = 0; i < 4; i++) {
        int mr = m0 + wm + i * 16 + quad * 4;
        int b = mr >> 11, s = mr & 2047;
        int cc = (s & 63) >> 3;
        long dst = ((long)(b * 16 + h) * 32 + (s >> 6)) * 8192 + d * 64 +
                   ((cc ^ (d & 7)) << 3) + (quad & 1) * 4;
        uint2 st;
        st.x = pack2bf_rn(acc[i][j][0] + bv, acc[i][j][1] + bv);
        st.y = pack2bf_rn(acc[i][j][2] + bv, acc[i][j][3] + bv);
        *(uint2*)&vp[dst] = st;
      }
    }
  }
}

// ---------- GEMM (BK=64): C = A . Bt^T + bias, f32 out ----------
__global__ __launch_bounds__(256) void gemm_bt_f32(
    const unsigned short* __restrict__ A,   // [M][K]
    const unsigned short* __restrict__ Bt,  // [N][K]
    const float* __restrict__ bias,         // [N]
    float* __restrict__ C, int K, int ldc) {
  __shared__ unsigned short As[128 * 64];
  __shared__ unsigned short Bs[128 * 64];
  const int m0 = blockIdx.y * 128, n0 = blockIdx.x * 128;
  const int tid = threadIdx.x, lane = tid & 63, wave = tid >> 6;
  const int wm = (wave >> 1) * 64, wn = (wave & 1) * 64;
  const int quad = lane >> 4, l15 = lane & 15;
  const int sw = l15 & 7;
  const int arow = wave * 8 + (lane >> 3);
  const int acol = ((lane & 7) ^ ((lane >> 3) & 7)) * 8;

  f32x4 acc[4][4] = {};
  const unsigned short* Ap = A + (long)(m0 + arow) * K + acol;
  const unsigned short* Bp = Bt + (long)(n0 + arow) * K + acol;
  unsigned short* AsW = As + wave * 512;
  unsigned short* BsW = Bs + wave * 512;

  for (int kb = 0; kb < K; kb += 64) {
    __syncthreads();
#pragma unroll
    for (int s = 0; s < 4; s++) {
      gll16(Ap + (long)s * 32 * K + kb, AsW + s * 2048);
      gll16(Bp + (long)s * 32 * K + kb, BsW + s * 2048);
    }
    __syncthreads();
#pragma unroll
    for (int ks = 0; ks < 2; ks++) {
      bf16x8 af[4], bfr[4];
#pragma unroll
      for (int t = 0; t < 4; t++)
        af[t] = *(const bf16x8*)&As[(wm + t * 16 + l15) * 64 + (((ks * 4 + quad) ^ sw) << 3)];
#pragma unroll
      for (int t = 0; t < 4; t++)
        bfr[t] = *(const bf16x8*)&Bs[(wn + t * 16 + l15) * 64 + (((ks * 4 + quad) ^ sw) << 3)];
#pragma unroll
      for (int i = 0; i < 4; i++)
#pragma unroll
        for (int j = 0; j < 4; j++)
          acc[i][j] = __builtin_amdgcn_mfma_f32_16x16x32_bf16(af[i], bfr[j], acc[i][j], 0, 0, 0);
    }
  }
#pragma unroll
  for (int j = 0; j < 4; j++) {
    int n = n0 + wn + j * 16 + l15;
    float bv = bias[n];
#pragma unroll
    for (int i = 0; i < 4; i++) {
      int mr = m0 + wm + i * 16 + quad * 4;
#pragma unroll
      for (int r = 0; r < 4; r++)
        C[(long)(mr + r) * ldc + n] = acc[i][j][r] + bv;
    }
  }
}

// ------- differential flash attention (S^T form, fixed-max, q32/wave, dbuf) -------
// 1-D grid 512, block 256 (4 waves). Wave w owns q rows [w*32, w*32+32).
// XCD swizzle: wgid = (bid&7)*64 + (bid>>3) -> XCD j owns 4 (b,h) K/V streams
// x 16 q-tiles -> 16-way L2 reuse (proven FETCH 139->25MB).
// T5 setprio around MFMA clusters: 4 barrier-free waves + 2 independent
// blocks/CU give the CU scheduler role diversity to arbitrate (m191 regime).
__global__ __launch_bounds__(256, 2) void attn_k(
    const unsigned short* __restrict__ qQ,   // [B*S][2048] bf16 (q only)
    const unsigned short* __restrict__ k1p,  // packed swizzled tiles
    const unsigned short* __restrict__ k2p,
    const unsigned short* __restrict__ vp,
    const float* __restrict__ mask,          // [B][S] f32
    const float* __restrict__ lamp,          // [1] f32
    unsigned short* __restrict__ out) {      // [B*S][2048] bf16
  __shared__ unsigned short k1s[2 * 4096];
  __shared__ unsigned short k2s[2 * 4096];
  __shared__ unsigned short vts[2 * 8192];
  __shared__ unsigned short pls[4 * 2048];  // [wave][qt*2+st][q16 x k32 swizzled]
  const int bid = blockIdx.x;
  const int wgid = (bid & 7) * 64 + (bid >> 3);
  const int bh = wgid >> 4;                 // 0..31 = b*16+h
  const int q0 = (wgid & 15) * 128;
  const int b = bh >> 4, h = bh & 15;
  const int tid = threadIdx.x, lane = tid & 63, wave = tid >> 6;
  const int quad = lane >> 4, l15 = lane & 15;
  const long rowq = (long)b * 2048 + q0;
  const int sw = l15 & 7;

  // Q fragments (B-operand layout), 2 q-tiles per wave, straight from global
  bf16x8 aq1[2][2], aq2[2][2];
#pragma unroll
  for (int qt = 0; qt < 2; qt++) {
    const unsigned short* qr =
        qQ + (rowq + wave * 32 + qt * 16 + l15) * 2048 + h * 64 + quad * 8;
    aq1[qt][0] = *(const bf16x8*)qr;
    aq1[qt][1] = *(const bf16x8*)(qr + 32);
    aq2[qt][0] = *(const bf16x8*)(qr + 1024);
    aq2[qt][1] = *(const bf16x8*)(qr + 1056);
  }
  f32x4 o1[2][8] = {}, o2[2][8] = {};
  // l-sums accumulated via ones-MFMA: C[col=l15] = sum_k P^T[k][col], dup'd over rows
  f32x4 l1a[2] = {}, l2a[2] = {};
  bf16x8 ones;
#pragma unroll
  for (int e = 0; e < 8; e++) ones[e] = (short)0x3F80;  // bf16 1.0
  // log2e-scaled domain, fixed max 0: p = exp2(s*SL + (1-m)*(-1e4*log2e))
  const float SL = 0.08838834764831845f * 1.4426950408889634f;
  const float ML = 1.4426950408889634e4f;
  const long tb = (long)bh * 32;
  unsigned short* pw = pls + wave * 2048;

  // initial stage of tile 0 into buffer 0
  {
    const unsigned short* k1t = k1p + tb * 4096 + tid * 8;
    const unsigned short* k2t = k2p + tb * 4096 + tid * 8;
    const unsigned short* vtt = vp + tb * 8192 + tid * 8;
    gll16(k1t, k1s + wave * 512);
    gll16(k1t + 2048, k1s + 2048 + wave * 512);
    gll16(k2t, k2s + wave * 512);
    gll16(k2t + 2048, k2s + 2048 + wave * 512);
#pragma unroll
    for (int rr = 0; rr < 4; rr++)
      gll16(vtt + rr * 2048, vts + rr * 2048 + wave * 512);
  }

  for (int t = 0; t < 32; t++) {
    const int cb = t & 1;
    __syncthreads();  // drains vmcnt: tile t staged; buffer cb^1 free
    // mask loads FIRST: oldest in vmcnt queue, so waiting for them does not
    // force the 12 prefetch global_load_lds to retire mid-iteration
    float4 mq[4];
#pragma unroll
    for (int nt = 0; nt < 4; nt++)
      mq[nt] = *(const float4*)(mask + (long)b * 2048 + t * 64 + nt * 16 + quad * 4);
    if (t < 31) {     // prefetch tile t+1 into other buffer
      const unsigned short* k1t = k1p + (tb + t + 1) * 4096 + tid * 8;
      const unsigned short* k2t = k2p + (tb + t + 1) * 4096 + tid * 8;
      const unsigned short* vtt = vp + (tb + t + 1) * 8192 + tid * 8;
      unsigned short* d1 = k1s + (cb ^ 1) * 4096 + wave * 512;
      unsigned short* d2 = k2s + (cb ^ 1) * 4096 + wave * 512;
      unsigned short* dv = vts + (cb ^ 1) * 8192 + wave * 512;
      gll16(k1t, d1);
      gll16(k1t + 2048, d1 + 2048);
      gll16(k2t, d2);
      gll16(k2t + 2048, d2 + 2048);
#pragma unroll
      for (int rr = 0; rr < 4; rr++)
        gll16(vtt + rr * 2048, dv + rr * 2048);
    }

#pragma unroll
    for (int half = 0; half < 2; half++) {
      // S^T = K . Q^T for k-half (32 k rows): C row=k (quad*4+r), col=q (l15)
      f32x4 s1[2][2] = {}, s2[2][2] = {};
      __builtin_amdgcn_s_setprio(1);
#pragma unroll
      for (int np = 0; np < 2; np++) {
        const int row = cb * 4096 + (half * 32 + np * 16 + l15) * 64;
#pragma unroll
        for (int ks = 0; ks < 2; ks++) {
          const int p = ((ks * 4 + quad) ^ sw) * 8;
          bf16x8 kf1 = *(const bf16x8*)&k1s[row + p];
          bf16x8 kf2 = *(const bf16x8*)&k2s[row + p];
#pragma unroll
          for (int qt = 0; qt < 2; qt++) {
            s1[qt][np] = __builtin_amdgcn_mfma_f32_16x16x32_bf16(kf1, aq1[qt][ks], s1[qt][np], 0, 0, 0);
            s2[qt][np] = __builtin_amdgcn_mfma_f32_16x16x32_bf16(kf2, aq2[qt][ks], s2[qt][np], 0, 0, 0);
          }
        }
      }
      __builtin_amdgcn_s_setprio(0);
      // fixed-max softmax: p = exp2(s*SL + ma) via raw v_exp_f32
      float ma[2][4];
#pragma unroll
      for (int np = 0; np < 2; np++)
#pragma unroll
        for (int r = 0; r < 4; r++)
          ma[np][r] = fmaf(((const float*)&mq[half * 2 + np])[r], ML, -ML);
#pragma unroll
      for (int qt = 0; qt < 2; qt++)
#pragma unroll
        for (int np = 0; np < 2; np++) {
          // write slot s4 = k'>>2 = np*4+quad, physical pos (s4 ^ (l15&7))*4:
          // bank-pair = 8*(l15&1) + (s4^x) is injective -> optimal 4-way for b64
          const int addr = l15 * 32 + (((np * 4 + quad) ^ sw) << 2);
          uint2 w1, w2;
          w1.x = cvtpk(fexp2(fmaf(s1[qt][np][0], SL, ma[np][0])),
                       fexp2(fmaf(s1[qt][np][1], SL, ma[np][1])));
          w1.y = cvtpk(fexp2(fmaf(s1[qt][np][2], SL, ma[np][2])),
                       fexp2(fmaf(s1[qt][np][3], SL, ma[np][3])));
          w2.x = cvtpk(fexp2(fmaf(s2[qt][np][0], SL, ma[np][0])),
                       fexp2(fmaf(s2[qt][np][1], SL, ma[np][1])));
          w2.y = cvtpk(fexp2(fmaf(s2[qt][np][2], SL, ma[np][2])),
                       fexp2(fmaf(s2[qt][np][3], SL, ma[np][3])));
          *(uint2*)&pw[(qt * 2 + 0) * 512 + addr] = w1;
          *(uint2*)&pw[(qt * 2 + 1) * 512 + addr] = w2;
        }
      // (no explicit lgkm drain: per-wave DS in-order + compiler counted waits)
      // PV for this k-half: O^T += V^T . P^T  (V frag shared by 2qt x 2streams)
      bf16x8 f1[2], f2[2];
      {
        const int ra = l15 * 32 + (((quad * 2 + 0) ^ sw) << 2);
        const int rb = l15 * 32 + (((quad * 2 + 1) ^ sw) << 2);
#pragma unroll
        for (int qt = 0; qt < 2; qt++) {
          union { bf16x8 v; uint2 u2[2]; } g1, g2;
          g1.u2[0] = *(const uint2*)&pw[(qt * 2 + 0) * 512 + ra];
          g1.u2[1] = *(const uint2*)&pw[(qt * 2 + 0) * 512 + rb];
          g2.u2[0] = *(const uint2*)&pw[(qt * 2 + 1) * 512 + ra];
          g2.u2[1] = *(const uint2*)&pw[(qt * 2 + 1) * 512 + rb];
          f1[qt] = g1.v; f2[qt] = g2.v;
        }
      }
      __builtin_amdgcn_s_setprio(1);
      // l-sums: ones(16x32) . P^T -> every lane gets full 32-k column sum for q=l15
#pragma unroll
      for (int qt = 0; qt < 2; qt++) {
        l1a[qt] = __builtin_amdgcn_mfma_f32_16x16x32_bf16(ones, f1[qt], l1a[qt], 0, 0, 0);
        l2a[qt] = __builtin_amdgcn_mfma_f32_16x16x32_bf16(ones, f2[qt], l2a[qt], 0, 0, 0);
      }
#pragma unroll
      for (int dn = 0; dn < 8; dn++) {
        const int pp = ((half * 4 + quad) ^ sw) * 8;
        bf16x8 vf = *(const bf16x8*)&vts[cb * 8192 + (dn * 16 + l15) * 64 + pp];
#pragma unroll
        for (int qt = 0; qt < 2; qt++) {
          o1[qt][dn] = __builtin_amdgcn_mfma_f32_16x16x32_bf16(vf, f1[qt], o1[qt][dn], 0, 0, 0);
          o2[qt][dn] = __builtin_amdgcn_mfma_f32_16x16x32_bf16(vf, f2[qt], o2[qt][dn], 0, 0, 0);
        }
      }
      __builtin_amdgcn_s_setprio(0);
      // (no post-PV drain: pw rewrite next half is same-wave, DS in-order)
    }
  }
  // epilogue: out = O1/l1 - lam*O2/l2 (l already full sums, no reduce needed)
  float lam = lamp[0];
#pragma unroll
  for (int qt = 0; qt < 2; qt++) {
    float i1 = 1.f / l1a[qt][0], i2 = lam / l2a[qt][0];
    unsigned short* orow =
        out + (rowq + wave * 32 + qt * 16 + l15) * 2048 + h * 128 + quad * 4;
#pragma unroll
    for (int dn = 0; dn < 8; dn++) {
      uint2 st;
      st.x = cvtpk(o1[qt][dn][0] * i1 - o2[qt][dn][0] * i2,
                   o1[qt][dn][1] * i1 - o2[qt][dn][1] * i2);
      st.y = cvtpk(o1[qt][dn][2] * i1 - o2[qt][dn][2] * i2,
                   o1[qt][dn][3] * i1 - o2[qt][dn][3] * i2);
      *(uint2*)(orow + dn * 16) = st;
    }
  }
}

extern "C" void kernel_launch(void* const* d_in, const int* in_sizes, int n_in,
                              void* d_out, int out_size, void* d_ws, size_t ws_size,
                              hipStream_t stream) {
  (void)in_sizes; (void)n_in; (void)out_size; (void)ws_size;
  const float* hs   = (const float*)d_in[0];
  const float* mask = (const float*)d_in[1];
  const float* Wa   = (const float*)d_in[2];
  const float* ba   = (const float*)d_in[3];
  const float* Wp   = (const float*)d_in[4];
  const float* bp   = (const float*)d_in[5];
  const float* lam  = (const float*)d_in[6];
  float* out = (float*)d_out;
  unsigned short* ws = (unsigned short*)d_ws;

  // workspace (bf16 elems): 48Mi elems = 96 MiB
  unsigned short* hsb = ws;                                  // [4096][2048] (aliased by att)
  unsigned short* WtA = hsb + (long)4096 * 2048;             // [6144][2048]
  unsigned short* WtP = WtA + (long)6144 * 2048;             // [2048][2048]
  unsigned short* qQ  = WtP + (long)2048 * 2048;             // [4096][2048]
  unsigned short* K1p = qQ + (long)4096 * 2048;              // 2*16*32 tiles * 4096
  unsigned short* K2p = K1p + (long)2 * 16 * 2048 * 64;
  unsigned short* Vp  = K2p + (long)2 * 16 * 2048 * 64;      // 2*16*32 tiles * 8192
  unsigned short* att = hsb;                                 // alias (hsb dead after step 2)

  // 1) fused cast + weight transposes (1 launch)
  prep_k<<<20480, 256, 0, stream>>>(hs, hsb, Wa, WtA, Wp, WtP);
  // 2) qkv GEMM (BK=64, synchronous staging), 2-D grid
  gemm_qkv<<<dim3(48, 32), 256, 0, stream>>>(hsb, WtA, ba, qQ, K1p, K2p, Vp);
  // 3) differential flash attention (XCD-swizzled 1-D grid, 4 waves x 32q, T5)
  attn_k<<<512, 256, 0, stream>>>(qQ, K1p, K2p, Vp, mask, lam, att);
  // 4) out = att @ W_proj + b_proj (BK=64, synchronous staging, 2-D grid)
  gemm_bt_f32<<<dim3(16, 32), 256, 0, stream>>>(att, WtP, bp, out, 2048, 2048);
}